// Round 1
// baseline (3751.008 us; speedup 1.0000x reference)
//
#include <hip/hip_runtime.h>

#define S 2048
#define H 1024
#define NH 16
#define HD 64
#define WIN 512
#define SCALE 0.125f

// ---------------------------------------------------------------------------
// GEMM: C[M,N] = A[M,K] @ W[K,N], fp32, 128x128 tile, BK=8, 8x8 per thread.
// ---------------------------------------------------------------------------
__global__ __launch_bounds__(256)
void gemm_f32(const float* __restrict__ A, const float* __restrict__ W,
              float* __restrict__ C, int M, int K, int N) {
    __shared__ float sA[8][128];
    __shared__ float sB[8][128];
    const int tid = threadIdx.x;
    const int bx = blockIdx.x;   // n-tile
    const int by = blockIdx.y;   // m-tile
    const int tx = tid & 15, ty = tid >> 4;
    const int row0 = by * 128, col0 = bx * 128;

    float acc[8][8];
#pragma unroll
    for (int i = 0; i < 8; i++)
#pragma unroll
        for (int j = 0; j < 8; j++) acc[i][j] = 0.f;

    const int ar = tid >> 1;          // 0..127 (A tile row)
    const int ak = (tid & 1) * 4;     // 0 or 4 (A tile k)
    const int br = tid >> 5;          // 0..7   (B tile k)
    const int bc = (tid & 31) * 4;    // 0..124 (B tile col)

    for (int k0 = 0; k0 < K; k0 += 8) {
        float4 av = make_float4(0.f, 0.f, 0.f, 0.f);
        if (row0 + ar < M)
            av = *reinterpret_cast<const float4*>(&A[(size_t)(row0 + ar) * K + k0 + ak]);
        float4 bv = *reinterpret_cast<const float4*>(&W[(size_t)(k0 + br) * N + col0 + bc]);
        __syncthreads();  // previous iteration's LDS reads complete
        sA[ak + 0][ar] = av.x; sA[ak + 1][ar] = av.y;
        sA[ak + 2][ar] = av.z; sA[ak + 3][ar] = av.w;
        *reinterpret_cast<float4*>(&sB[br][bc]) = bv;
        __syncthreads();
#pragma unroll
        for (int kk = 0; kk < 8; kk++) {
            float4 a0 = *reinterpret_cast<const float4*>(&sA[kk][ty * 8]);
            float4 a1 = *reinterpret_cast<const float4*>(&sA[kk][ty * 8 + 4]);
            float4 b0 = *reinterpret_cast<const float4*>(&sB[kk][tx * 8]);
            float4 b1 = *reinterpret_cast<const float4*>(&sB[kk][tx * 8 + 4]);
            float a[8] = {a0.x, a0.y, a0.z, a0.w, a1.x, a1.y, a1.z, a1.w};
            float b[8] = {b0.x, b0.y, b0.z, b0.w, b1.x, b1.y, b1.z, b1.w};
#pragma unroll
            for (int i = 0; i < 8; i++)
#pragma unroll
                for (int j = 0; j < 8; j++)
                    acc[i][j] += a[i] * b[j];
        }
    }
#pragma unroll
    for (int i = 0; i < 8; i++) {
        int r = row0 + ty * 8 + i;
        if (r < M) {
#pragma unroll
            for (int j = 0; j < 8; j += 4) {
                *reinterpret_cast<float4*>(&C[(size_t)r * N + col0 + tx * 8 + j]) =
                    make_float4(acc[i][j], acc[i][j + 1], acc[i][j + 2], acc[i][j + 3]);
            }
        }
    }
}

// ---------------------------------------------------------------------------
// Flash-style attention, fp32. Block = 256 thr = (head, 32 query rows).
// Q,K,V,O layouts: [rows][H] with head offset h*HD (merged-head layout).
// MASK: 0 = none (cross), 1 = causal, 2 = causal + sliding window WIN.
// Thread (r = tid/8, g = tid%8): row r, score cols g*8..g*8+7, out dims same.
// ---------------------------------------------------------------------------
template <int MASK>
__global__ __launch_bounds__(256)
void attn_f32(const float* __restrict__ Q, const float* __restrict__ K,
              const float* __restrict__ V, float* __restrict__ O, int Skv) {
    __shared__ float qs[32][65];
    __shared__ float ks[64][65];
    __shared__ float vs[64][65];
    __shared__ float ps[32][65];
    const int tid = threadIdx.x;
    const int h = blockIdx.y;
    const int q0 = blockIdx.x * 32;
    const int r = tid >> 3;   // 0..31
    const int g = tid & 7;    // 0..7
    const int qi = q0 + r;

    {   // load Q tile (each thread: 8 contiguous dims of its row)
        const int lc = g * 8;
        const float* qp = &Q[(size_t)qi * H + h * HD + lc];
        float4 v0 = *reinterpret_cast<const float4*>(qp);
        float4 v1 = *reinterpret_cast<const float4*>(qp + 4);
        qs[r][lc + 0] = v0.x; qs[r][lc + 1] = v0.y; qs[r][lc + 2] = v0.z; qs[r][lc + 3] = v0.w;
        qs[r][lc + 4] = v1.x; qs[r][lc + 5] = v1.y; qs[r][lc + 6] = v1.z; qs[r][lc + 7] = v1.w;
    }

    float o[8];
#pragma unroll
    for (int j = 0; j < 8; j++) o[j] = 0.f;
    float m = -1e30f, l = 0.f;

    int ktEnd = (Skv + 63) >> 6;
    if (MASK >= 1) { int c = (q0 >> 6) + 1; if (c < ktEnd) ktEnd = c; }
    int ktBeg = 0;
    if (MASK == 2 && q0 >= WIN) ktBeg = (q0 - WIN) >> 6;

    const int rr = tid >> 2, cc = (tid & 3) * 16;

    for (int kt = ktBeg; kt < ktEnd; kt++) {
        __syncthreads();  // previous tile's LDS reads complete (also covers qs)
        {   // load K,V tiles (64x64)
            const float* kp = &K[(size_t)(kt * 64 + rr) * H + h * HD + cc];
            const float* vp = &V[(size_t)(kt * 64 + rr) * H + h * HD + cc];
#pragma unroll
            for (int j = 0; j < 16; j += 4) {
                float4 kv = *reinterpret_cast<const float4*>(kp + j);
                ks[rr][cc + j + 0] = kv.x; ks[rr][cc + j + 1] = kv.y;
                ks[rr][cc + j + 2] = kv.z; ks[rr][cc + j + 3] = kv.w;
                float4 vv = *reinterpret_cast<const float4*>(vp + j);
                vs[rr][cc + j + 0] = vv.x; vs[rr][cc + j + 1] = vv.y;
                vs[rr][cc + j + 2] = vv.z; vs[rr][cc + j + 3] = vv.w;
            }
        }
        __syncthreads();

        float sc[8];
#pragma unroll
        for (int j = 0; j < 8; j++) sc[j] = 0.f;
        for (int d = 0; d < 64; d++) {
            float qv = qs[r][d];
#pragma unroll
            for (int j = 0; j < 8; j++) sc[j] += qv * ks[g * 8 + j][d];
        }
#pragma unroll
        for (int j = 0; j < 8; j++) {
            float sv = sc[j] * SCALE;
            if (MASK >= 1) {
                int kj = kt * 64 + g * 8 + j;
                if (kj > qi) sv = -1e30f;
                if (MASK == 2 && (qi - kj) > WIN) sv = -1e30f;
            }
            sc[j] = sv;
        }
        // row max across the 8 lanes of this row
        float tm = sc[0];
#pragma unroll
        for (int j = 1; j < 8; j++) tm = fmaxf(tm, sc[j]);
        tm = fmaxf(tm, __shfl_xor(tm, 1));
        tm = fmaxf(tm, __shfl_xor(tm, 2));
        tm = fmaxf(tm, __shfl_xor(tm, 4));
        float mn = fmaxf(m, tm);
        float alpha = __expf(m - mn);
        float rs = 0.f;
#pragma unroll
        for (int j = 0; j < 8; j++) { float p = __expf(sc[j] - mn); sc[j] = p; rs += p; }
        rs += __shfl_xor(rs, 1);
        rs += __shfl_xor(rs, 2);
        rs += __shfl_xor(rs, 4);
        l = l * alpha + rs;
        m = mn;
#pragma unroll
        for (int j = 0; j < 8; j++) o[j] *= alpha;
#pragma unroll
        for (int j = 0; j < 8; j++) ps[r][g * 8 + j] = sc[j];
        __syncthreads();
        // PV: o[d] += sum_k p[r][k] * v[k][d], d = g*8..g*8+7
        for (int k = 0; k < 64; k++) {
            float pv = ps[r][k];
#pragma unroll
            for (int j = 0; j < 8; j++) o[j] += pv * vs[k][g * 8 + j];
        }
    }
    float inv = 1.f / l;
    float* op = &O[(size_t)qi * H + h * HD + g * 8];
#pragma unroll
    for (int j = 0; j < 8; j++) op[j] = o[j] * inv;
}

// ---------------------------------------------------------------------------
// Gate + fuse: per token, g = softmax(concat(outs) @ gate_w + gate_b),
// out = sum_b g[b] * outs[b]. One block per token.
// ---------------------------------------------------------------------------
__global__ __launch_bounds__(256)
void gate_fuse(const float* __restrict__ o0, const float* __restrict__ o1,
               const float* __restrict__ o2, const float* __restrict__ o3,
               const float* __restrict__ gw, const float* __restrict__ gb,
               float* __restrict__ out) {
    const int s = blockIdx.x;
    const int tid = threadIdx.x;
    const float* ob[4] = {o0 + (size_t)s * H, o1 + (size_t)s * H,
                          o2 + (size_t)s * H, o3 + (size_t)s * H};
    float p0 = 0.f, p1 = 0.f, p2 = 0.f, p3 = 0.f;
    for (int b = 0; b < 4; b++) {
        const float* obb = ob[b];
        const float* gwb = gw + (size_t)b * H * 4;
        for (int i = tid; i < H; i += 256) {
            float xv = obb[i];
            float4 g4 = *reinterpret_cast<const float4*>(&gwb[(size_t)i * 4]);
            p0 += xv * g4.x; p1 += xv * g4.y; p2 += xv * g4.z; p3 += xv * g4.w;
        }
    }
#pragma unroll
    for (int off = 1; off < 64; off <<= 1) {
        p0 += __shfl_xor(p0, off);
        p1 += __shfl_xor(p1, off);
        p2 += __shfl_xor(p2, off);
        p3 += __shfl_xor(p3, off);
    }
    __shared__ float red[4][4];
    if ((tid & 63) == 0) {
        int w = tid >> 6;
        red[w][0] = p0; red[w][1] = p1; red[w][2] = p2; red[w][3] = p3;
    }
    __syncthreads();
    float gl[4];
#pragma unroll
    for (int j = 0; j < 4; j++)
        gl[j] = gb[j] + red[0][j] + red[1][j] + red[2][j] + red[3][j];
    float mx = fmaxf(fmaxf(gl[0], gl[1]), fmaxf(gl[2], gl[3]));
    float e0 = __expf(gl[0] - mx), e1 = __expf(gl[1] - mx);
    float e2 = __expf(gl[2] - mx), e3 = __expf(gl[3] - mx);
    float inv = 1.f / (e0 + e1 + e2 + e3);
    e0 *= inv; e1 *= inv; e2 *= inv; e3 *= inv;
    int d = tid * 4;
    float4 a  = *reinterpret_cast<const float4*>(&ob[0][d]);
    float4 b4 = *reinterpret_cast<const float4*>(&ob[1][d]);
    float4 c  = *reinterpret_cast<const float4*>(&ob[2][d]);
    float4 dd = *reinterpret_cast<const float4*>(&ob[3][d]);
    float4 rv;
    rv.x = e0 * a.x + e1 * b4.x + e2 * c.x + e3 * dd.x;
    rv.y = e0 * a.y + e1 * b4.y + e2 * c.y + e3 * dd.y;
    rv.z = e0 * a.z + e1 * b4.z + e2 * c.z + e3 * dd.z;
    rv.w = e0 * a.w + e1 * b4.w + e2 * c.w + e3 * dd.w;
    *reinterpret_cast<float4*>(&out[(size_t)s * H + d]) = rv;
}

// ---------------------------------------------------------------------------
// Launch: per branch b: Q = x@wq, K = src@wk, V = src@wv, attn, @wo -> out4[b].
// Then gate+fuse. Workspace: 4*S*H (out4) + 4*S*H (Q,K,V,A scratch) = 64 MB.
// ---------------------------------------------------------------------------
extern "C" void kernel_launch(void* const* d_in, const int* in_sizes, int n_in,
                              void* d_out, int out_size, void* d_ws, size_t ws_size,
                              hipStream_t stream) {
    const float* Wm[16];
    for (int i = 0; i < 16; i++) Wm[i] = (const float*)d_in[i];
    const float* gw  = (const float*)d_in[16];
    const float* gb  = (const float*)d_in[17];
    const float* x   = (const float*)d_in[18];
    const float* mem = (const float*)d_in[19];
    const float* per = (const float*)d_in[20];
    float* out = (float*)d_out;
    float* ws  = (float*)d_ws;

    const size_t SH = (size_t)S * H;
    float* out4 = ws;             // 4 * S*H
    float* bufQ = ws + 4 * SH;
    float* bufK = bufQ + SH;
    float* bufV = bufK + SH;
    float* bufA = bufV + SH;

    dim3 blk(256);
    auto gemm = [&](const float* A, const float* Wp, float* C, int M) {
        dim3 grid(1024 / 128, (M + 127) / 128);
        gemm_f32<<<grid, blk, 0, stream>>>(A, Wp, C, M, 1024, 1024);
    };

    for (int b = 0; b < 4; b++) {
        const float* src = (b < 2) ? x : (b == 2 ? mem : per);
        int Mkv = (b < 2) ? 2048 : (b == 2 ? 512 : 64);
        gemm(x,   Wm[b * 4 + 0], bufQ, 2048);
        gemm(src, Wm[b * 4 + 1], bufK, Mkv);
        gemm(src, Wm[b * 4 + 2], bufV, Mkv);
        dim3 agrid(S / 32, NH);
        if (b == 0)
            attn_f32<2><<<agrid, blk, 0, stream>>>(bufQ, bufK, bufV, bufA, Mkv);
        else if (b == 1)
            attn_f32<1><<<agrid, blk, 0, stream>>>(bufQ, bufK, bufV, bufA, Mkv);
        else
            attn_f32<0><<<agrid, blk, 0, stream>>>(bufQ, bufK, bufV, bufA, Mkv);
        gemm(bufA, Wm[b * 4 + 3], out4 + (size_t)b * SH, 2048);
    }
    gate_fuse<<<dim3(S), blk, 0, stream>>>(out4, out4 + SH, out4 + 2 * SH,
                                           out4 + 3 * SH, gw, gb, out);
}

// Round 2
// 393.426 us; speedup vs baseline: 9.5342x; 9.5342x over previous
//
#include <hip/hip_runtime.h>

#define S 2048
#define H 1024
#define NH 16
#define HD 64
#define WIN 512
#define SCALE 0.125f

typedef unsigned short u16;
typedef __attribute__((ext_vector_type(8))) short bfrag;   // 8 bf16 (4 VGPRs)
typedef __attribute__((ext_vector_type(4))) float facc;    // 4 f32 acc
typedef __attribute__((ext_vector_type(4))) unsigned short u16x4;

__device__ __forceinline__ u16 f2bf(float f) {
    union { float f; unsigned u; } v; v.f = f;
    unsigned r = v.u + 0x7fffu + ((v.u >> 16) & 1u);   // RNE
    return (u16)(r >> 16);
}
__device__ __forceinline__ float bf2f(u16 b) {
    union { unsigned u; float f; } v; v.u = ((unsigned)b) << 16;
    return v.f;
}

// ---------------------------------------------------------------------------
// fp32 -> bf16 cast, 8 elems/thread
// ---------------------------------------------------------------------------
__global__ __launch_bounds__(256)
void cast_bf16(const float* __restrict__ in, u16* __restrict__ out, int n8) {
    int i = blockIdx.x * 256 + threadIdx.x;
    if (i >= n8) return;
    const float4* p = reinterpret_cast<const float4*>(in) + (size_t)i * 2;
    float4 a = p[0], b = p[1];
    u16x4 o0, o1;
    o0[0] = f2bf(a.x); o0[1] = f2bf(a.y); o0[2] = f2bf(a.z); o0[3] = f2bf(a.w);
    o1[0] = f2bf(b.x); o1[1] = f2bf(b.y); o1[2] = f2bf(b.z); o1[3] = f2bf(b.w);
    u16x4* q = reinterpret_cast<u16x4*>(out) + (size_t)i * 2;
    q[0] = o0; q[1] = o1;
}

// ---------------------------------------------------------------------------
// Wt[z][n][k] = W_z[k][n] as bf16 (transpose+cast), 64x64 LDS tiles, z = 0..3
// ---------------------------------------------------------------------------
__global__ __launch_bounds__(256)
void transp_cast(const float* __restrict__ w0, const float* __restrict__ w1,
                 const float* __restrict__ w2, const float* __restrict__ w3,
                 u16* __restrict__ wt) {
    __shared__ float t[64][65];
    const float* w = blockIdx.z == 0 ? w0 : blockIdx.z == 1 ? w1
                   : blockIdx.z == 2 ? w2 : w3;
    u16* o = wt + (size_t)blockIdx.z * (1024 * 1024);
    const int kt = blockIdx.y * 64, nt = blockIdx.x * 64;
    const int r = threadIdx.x >> 4, c4 = (threadIdx.x & 15) * 4;
#pragma unroll
    for (int p = 0; p < 4; p++) {
        float4 v = *reinterpret_cast<const float4*>(
            &w[(size_t)(kt + r + p * 16) * 1024 + nt + c4]);
        t[r + p * 16][c4 + 0] = v.x; t[r + p * 16][c4 + 1] = v.y;
        t[r + p * 16][c4 + 2] = v.z; t[r + p * 16][c4 + 3] = v.w;
    }
    __syncthreads();
#pragma unroll
    for (int p = 0; p < 4; p++) {
        int nn = r + p * 16;
        u16x4 ov;
        ov[0] = f2bf(t[c4 + 0][nn]); ov[1] = f2bf(t[c4 + 1][nn]);
        ov[2] = f2bf(t[c4 + 2][nn]); ov[3] = f2bf(t[c4 + 3][nn]);
        *reinterpret_cast<u16x4*>(&o[(size_t)(nt + nn) * 1024 + kt + c4]) = ov;
    }
}

// ---------------------------------------------------------------------------
// bf16 MFMA GEMM: C[M,1024] = A[M,1024] @ W, with Bt[n][k] = W[k][n].
// 128x128 tile, BK=64, 4 waves (2x2, 64x64 each), mfma_f32_16x16x32_bf16.
// LDS XOR-swizzle: lds[row][chunk ^ (row&7)] (chunk = k/8) -> conflict-free
// ds_read_b128 fragments. z selects Bt (+z*sB) and C (+z*sC).
// ---------------------------------------------------------------------------
__global__ __launch_bounds__(256)
void gemm_bf16(const u16* __restrict__ A, const u16* __restrict__ Bt,
               u16* __restrict__ C, int M, long sB, long sC) {
    __shared__ __align__(16) u16 sa[128 * 64];
    __shared__ __align__(16) u16 sb[128 * 64];
    const int tid = threadIdx.x;
    const int wid = tid >> 6, lane = tid & 63;
    const int lhi = lane >> 4, llo = lane & 15;
    const int wm = wid >> 1, wn = wid & 1;
    const int row0 = blockIdx.y * 128, col0 = blockIdx.x * 128;
    Bt += (size_t)blockIdx.z * sB;
    C += (size_t)blockIdx.z * sC;

    facc acc[4][4];
#pragma unroll
    for (int i = 0; i < 4; i++)
#pragma unroll
        for (int j = 0; j < 4; j++)
#pragma unroll
            for (int k = 0; k < 4; k++) acc[i][j][k] = 0.f;

    int arow[4];
#pragma unroll
    for (int j = 0; j < 4; j++) {
        int r = (j * 256 + tid) >> 3;
        int ar = row0 + r; if (ar > M - 1) ar = M - 1;   // clamp (M<128 tiles)
        arow[j] = ar;
    }
    bfrag ra[4], rb[4];
    auto load_tile = [&](int k0) {
#pragma unroll
        for (int j = 0; j < 4; j++) {
            int idx = j * 256 + tid;
            int c = idx & 7, r = idx >> 3;
            ra[j] = *reinterpret_cast<const bfrag*>(&A[(size_t)arow[j] * 1024 + k0 + c * 8]);
            rb[j] = *reinterpret_cast<const bfrag*>(&Bt[(size_t)(col0 + r) * 1024 + k0 + c * 8]);
        }
    };
    load_tile(0);
    for (int kt = 0; kt < 16; kt++) {
        __syncthreads();
#pragma unroll
        for (int j = 0; j < 4; j++) {
            int idx = j * 256 + tid;
            int c = idx & 7, r = idx >> 3;
            int p = c ^ (r & 7);
            *reinterpret_cast<bfrag*>(&sa[r * 64 + p * 8]) = ra[j];
            *reinterpret_cast<bfrag*>(&sb[r * 64 + p * 8]) = rb[j];
        }
        __syncthreads();
        if (kt < 15) load_tile((kt + 1) * 64);   // prefetch overlaps compute
#pragma unroll
        for (int ks = 0; ks < 2; ks++) {
            bfrag af[4], bfv[4];
#pragma unroll
            for (int mf = 0; mf < 4; mf++) {
                int r = wm * 64 + mf * 16 + llo;
                int p = (ks * 4 + lhi) ^ (r & 7);
                af[mf] = *reinterpret_cast<const bfrag*>(&sa[r * 64 + p * 8]);
            }
#pragma unroll
            for (int nf = 0; nf < 4; nf++) {
                int r = wn * 64 + nf * 16 + llo;
                int p = (ks * 4 + lhi) ^ (r & 7);
                bfv[nf] = *reinterpret_cast<const bfrag*>(&sb[r * 64 + p * 8]);
            }
#pragma unroll
            for (int mf = 0; mf < 4; mf++)
#pragma unroll
                for (int nf = 0; nf < 4; nf++)
                    acc[mf][nf] = __builtin_amdgcn_mfma_f32_16x16x32_bf16(
                        af[mf], bfv[nf], acc[mf][nf], 0, 0, 0);
        }
    }
#pragma unroll
    for (int mf = 0; mf < 4; mf++) {
#pragma unroll
        for (int r = 0; r < 4; r++) {
            int row = row0 + wm * 64 + mf * 16 + lhi * 4 + r;
            if (row < M) {
#pragma unroll
                for (int nf = 0; nf < 4; nf++) {
                    int col = col0 + wn * 64 + nf * 16 + llo;
                    C[(size_t)row * 1024 + col] = f2bf(acc[mf][nf][r]);
                }
            }
        }
    }
}

// ---------------------------------------------------------------------------
// Flash attention, bf16 MFMA. Block = 256 thr = 4 waves x 16 query rows.
// QBLK=64, KBLK=64. Q in regs; K LDS-swizzled; V transposed+swizzled in LDS;
// P round-trips through per-wave LDS region (no cross-wave barrier needed).
// MASK: 0=cross, 1=causal, 2=causal+window. Tile-skip + boundary-only mask.
// ---------------------------------------------------------------------------
template <int MASK>
__global__ __launch_bounds__(256)
void attn_mfma(const u16* __restrict__ Q, const u16* __restrict__ K,
               const u16* __restrict__ V, u16* __restrict__ O, int Skv) {
    __shared__ __align__(16) u16 ksm[64 * 64];
    __shared__ __align__(16) u16 vtm[64 * 64];
    __shared__ __align__(16) u16 psm[4 * 16 * 64];
    const int tid = threadIdx.x, wid = tid >> 6, lane = tid & 63;
    const int lhi = lane >> 4, llo = lane & 15;
    const int h = blockIdx.y, q0 = blockIdx.x * 64;
    const int hoff = h * 64;

    bfrag qf[2];
    {
        const u16* qp = &Q[(size_t)(q0 + wid * 16 + llo) * 1024 + hoff + lhi * 8];
        qf[0] = *reinterpret_cast<const bfrag*>(qp);
        qf[1] = *reinterpret_cast<const bfrag*>(qp + 32);
    }
    facc acc_o[4];
    float m_r[4], l_r[4];
#pragma unroll
    for (int r = 0; r < 4; r++) { m_r[r] = -1e30f; l_r[r] = 0.f; }
#pragma unroll
    for (int nf = 0; nf < 4; nf++)
#pragma unroll
        for (int k = 0; k < 4; k++) acc_o[nf][k] = 0.f;

    const int qt = q0 >> 6;
    const int ktEnd = (MASK >= 1) ? (qt + 1) : (Skv >> 6);
    const int ktBeg = (MASK == 2 && q0 >= WIN) ? ((q0 - WIN) >> 6) : 0;
    const int vkey = tid & 63, vdb = (tid >> 6) * 16;

    for (int kt = ktBeg; kt < ktEnd; kt++) {
        bfrag rk[2], rv[2];
#pragma unroll
        for (int j = 0; j < 2; j++) {
            int idx = j * 256 + tid;
            int key = idx >> 3, c = idx & 7;
            rk[j] = *reinterpret_cast<const bfrag*>(
                &K[(size_t)(kt * 64 + key) * 1024 + hoff + c * 8]);
        }
        {
            const u16* vp = &V[(size_t)(kt * 64 + vkey) * 1024 + hoff + vdb];
            rv[0] = *reinterpret_cast<const bfrag*>(vp);
            rv[1] = *reinterpret_cast<const bfrag*>(vp + 8);
        }
        __syncthreads();   // all waves done reading prev tile's ksm/vtm
#pragma unroll
        for (int j = 0; j < 2; j++) {
            int idx = j * 256 + tid;
            int key = idx >> 3, c = idx & 7;
            *reinterpret_cast<bfrag*>(&ksm[key * 64 + (c ^ (key & 7)) * 8]) = rk[j];
        }
        {
            int kc = vkey >> 3, kp = vkey & 7;
#pragma unroll
            for (int j = 0; j < 2; j++)
#pragma unroll
                for (int i = 0; i < 8; i++) {
                    int d = vdb + j * 8 + i;
                    vtm[d * 64 + ((kc ^ (d & 7)) * 8 + kp)] = (u16)(unsigned short)rv[j][i];
                }
        }
        __syncthreads();

        // S = Q K^T  (D rows = queries, cols = keys)
        facc sc[4];
#pragma unroll
        for (int nf = 0; nf < 4; nf++) {
#pragma unroll
            for (int k = 0; k < 4; k++) sc[nf][k] = 0.f;
#pragma unroll
            for (int ks = 0; ks < 2; ks++) {
                int r = nf * 16 + llo;
                int p = (ks * 4 + lhi) ^ (r & 7);
                bfrag kf = *reinterpret_cast<const bfrag*>(&ksm[r * 64 + p * 8]);
                sc[nf] = __builtin_amdgcn_mfma_f32_16x16x32_bf16(qf[ks], kf, sc[nf], 0, 0, 0);
            }
        }
        float s[4][4];
#pragma unroll
        for (int nf = 0; nf < 4; nf++)
#pragma unroll
            for (int r = 0; r < 4; r++) s[nf][r] = sc[nf][r] * SCALE;

        const bool diag = (MASK >= 1) && (kt == qt);
        const bool wedge = (MASK == 2) && (q0 >= WIN) && (kt == ktBeg);
        if (diag || wedge) {
#pragma unroll
            for (int nf = 0; nf < 4; nf++)
#pragma unroll
                for (int r = 0; r < 4; r++) {
                    int key = kt * 64 + nf * 16 + llo;
                    int qi = q0 + wid * 16 + lhi * 4 + r;
                    if ((diag && key > qi) || (wedge && (qi - key) > WIN))
                        s[nf][r] = -1e30f;
                }
        }
        // online softmax, rows reduce across 16-lane groups
        float alpha[4];
#pragma unroll
        for (int r = 0; r < 4; r++) {
            float mx = fmaxf(fmaxf(s[0][r], s[1][r]), fmaxf(s[2][r], s[3][r]));
            mx = fmaxf(mx, __shfl_xor(mx, 1));
            mx = fmaxf(mx, __shfl_xor(mx, 2));
            mx = fmaxf(mx, __shfl_xor(mx, 4));
            mx = fmaxf(mx, __shfl_xor(mx, 8));
            float mn = fmaxf(m_r[r], mx);
            alpha[r] = __expf(m_r[r] - mn);
            m_r[r] = mn;
            float rs = 0.f;
#pragma unroll
            for (int nf = 0; nf < 4; nf++) {
                float pv = __expf(s[nf][r] - mn);
                s[nf][r] = pv; rs += pv;
            }
            rs += __shfl_xor(rs, 1);
            rs += __shfl_xor(rs, 2);
            rs += __shfl_xor(rs, 4);
            rs += __shfl_xor(rs, 8);
            l_r[r] = l_r[r] * alpha[r] + rs;
        }
#pragma unroll
        for (int nf = 0; nf < 4; nf++)
#pragma unroll
            for (int r = 0; r < 4; r++) acc_o[nf][r] *= alpha[r];

        // P (D layout) -> per-wave LDS (swizzled) -> A-fragment layout
        u16* pw = &psm[wid * 1024];
#pragma unroll
        for (int nf = 0; nf < 4; nf++) {
            int kc = nf * 2 + (llo >> 3), kp = llo & 7;
#pragma unroll
            for (int r = 0; r < 4; r++) {
                int row = lhi * 4 + r;
                pw[row * 64 + ((kc ^ (row & 7)) * 8 + kp)] = f2bf(s[nf][r]);
            }
        }
        // PV (wave-local P, no barrier needed)
#pragma unroll
        for (int ks = 0; ks < 2; ks++) {
            int pp = (ks * 4 + lhi) ^ (llo & 7);
            bfrag pf = *reinterpret_cast<const bfrag*>(&pw[llo * 64 + pp * 8]);
#pragma unroll
            for (int nf = 0; nf < 4; nf++) {
                int d = nf * 16 + llo;
                int vp2 = (ks * 4 + lhi) ^ (d & 7);
                bfrag vf = *reinterpret_cast<const bfrag*>(&vtm[d * 64 + vp2 * 8]);
                acc_o[nf] = __builtin_amdgcn_mfma_f32_16x16x32_bf16(pf, vf, acc_o[nf], 0, 0, 0);
            }
        }
    }
#pragma unroll
    for (int r = 0; r < 4; r++) {
        float inv = 1.f / l_r[r];
#pragma unroll
        for (int nf = 0; nf < 4; nf++) {
            int row = q0 + wid * 16 + lhi * 4 + r;
            int col = hoff + nf * 16 + llo;
            O[(size_t)row * 1024 + col] = f2bf(acc_o[nf][r] * inv);
        }
    }
}

// ---------------------------------------------------------------------------
// Gate + fuse (out4 in bf16): g = softmax(concat(outs) @ gate_w + gate_b),
// out = sum_b g[b] * outs[b]. One block per token.
// ---------------------------------------------------------------------------
__global__ __launch_bounds__(256)
void gate_fuse(const u16* __restrict__ o4, const float* __restrict__ gw,
               const float* __restrict__ gb, float* __restrict__ out) {
    const size_t SHsz = (size_t)S * H;
    const int s = blockIdx.x, tid = threadIdx.x;
    const u16* ob0 = o4 + (size_t)s * H;
    float p[4] = {0.f, 0.f, 0.f, 0.f};
    for (int b = 0; b < 4; b++) {
        const u16* obb = ob0 + b * SHsz;
        const float* gwb = gw + (size_t)b * H * 4;
        for (int i = tid; i < H; i += 256) {
            float xv = bf2f(obb[i]);
            float4 g4 = *reinterpret_cast<const float4*>(&gwb[(size_t)i * 4]);
            p[0] += xv * g4.x; p[1] += xv * g4.y;
            p[2] += xv * g4.z; p[3] += xv * g4.w;
        }
    }
#pragma unroll
    for (int off = 1; off < 64; off <<= 1)
#pragma unroll
        for (int j = 0; j < 4; j++) p[j] += __shfl_xor(p[j], off);
    __shared__ float red[4][4];
    if ((tid & 63) == 0) {
        int w = tid >> 6;
#pragma unroll
        for (int j = 0; j < 4; j++) red[w][j] = p[j];
    }
    __syncthreads();
    float gl[4];
#pragma unroll
    for (int j = 0; j < 4; j++)
        gl[j] = gb[j] + red[0][j] + red[1][j] + red[2][j] + red[3][j];
    float mx = fmaxf(fmaxf(gl[0], gl[1]), fmaxf(gl[2], gl[3]));
    float e[4]; float tot = 0.f;
#pragma unroll
    for (int j = 0; j < 4; j++) { e[j] = __expf(gl[j] - mx); tot += e[j]; }
    float inv = 1.f / tot;
    int d = tid * 4;
    float4 rv; rv.x = rv.y = rv.z = rv.w = 0.f;
#pragma unroll
    for (int b = 0; b < 4; b++) {
        const u16* obb = ob0 + b * SHsz + d;
        float wgt = e[b] * inv;
        rv.x += wgt * bf2f(obb[0]);
        rv.y += wgt * bf2f(obb[1]);
        rv.z += wgt * bf2f(obb[2]);
        rv.w += wgt * bf2f(obb[3]);
    }
    *reinterpret_cast<float4*>(&out[(size_t)s * H + d]) = rv;
}

// ---------------------------------------------------------------------------
// Orchestration. WS (bf16 elems): Wt 4Mi | xb 2Mi | memb 0.5Mi | perb 64Ki |
// qkv 6Mi | out4 8Mi  => ~41 MB. Attn output aliases Q (per-block read-then-
// write of the identical region => safe).
// ---------------------------------------------------------------------------
extern "C" void kernel_launch(void* const* d_in, const int* in_sizes, int n_in,
                              void* d_out, int out_size, void* d_ws, size_t ws_size,
                              hipStream_t stream) {
    const float* Wm[16];
    for (int i = 0; i < 16; i++) Wm[i] = (const float*)d_in[i];
    const float* gw = (const float*)d_in[16];
    const float* gb = (const float*)d_in[17];
    const float* x = (const float*)d_in[18];
    const float* mem = (const float*)d_in[19];
    const float* per = (const float*)d_in[20];
    float* out = (float*)d_out;
    u16* w16 = (u16*)d_ws;

    const size_t MEL = 1024 * 1024;
    const size_t SH = (size_t)S * H;
    u16* Wt = w16;                       // 4*MEL
    u16* xb = Wt + 4 * MEL;              // SH
    u16* memb = xb + SH;                 // 512*1024
    u16* perb = memb + 512 * 1024;       // 64*1024
    u16* qkv = perb + 64 * 1024;         // 3*SH  [Q | K | V]
    u16* out4 = qkv + 3 * SH;            // 4*SH

    dim3 blk(256);
    cast_bf16<<<dim3(1024), blk, 0, stream>>>(x, xb, (int)(SH / 8));
    cast_bf16<<<dim3(256), blk, 0, stream>>>(mem, memb, 512 * 1024 / 8);
    cast_bf16<<<dim3(32), blk, 0, stream>>>(per, perb, 64 * 1024 / 8);

    for (int b = 0; b < 4; b++) {
        transp_cast<<<dim3(16, 16, 4), blk, 0, stream>>>(
            Wm[b * 4 + 0], Wm[b * 4 + 1], Wm[b * 4 + 2], Wm[b * 4 + 3], Wt);
        if (b < 2) {
            // Q,K,V fused: z=0/1/2 -> wq/wk/wv, outputs qkv[0/1/2]
            gemm_bf16<<<dim3(8, 16, 3), blk, 0, stream>>>(
                xb, Wt, qkv, 2048, (long)MEL, (long)SH);
        } else {
            gemm_bf16<<<dim3(8, 16, 1), blk, 0, stream>>>(
                xb, Wt, qkv, 2048, 0, 0);
            const u16* src = (b == 2) ? memb : perb;
            int Mkv = (b == 2) ? 512 : 64;
            gemm_bf16<<<dim3(8, (Mkv + 127) / 128, 2), blk, 0, stream>>>(
                src, Wt + MEL, qkv + SH, Mkv, (long)MEL, (long)SH);
        }
        int Skv = (b < 2) ? 2048 : (b == 2 ? 512 : 64);
        dim3 ag(32, 16);
        if (b == 0)
            attn_mfma<2><<<ag, blk, 0, stream>>>(qkv, qkv + SH, qkv + 2 * SH, qkv, Skv);
        else if (b == 1)
            attn_mfma<1><<<ag, blk, 0, stream>>>(qkv, qkv + SH, qkv + 2 * SH, qkv, Skv);
        else
            attn_mfma<0><<<ag, blk, 0, stream>>>(qkv, qkv + SH, qkv + 2 * SH, qkv, Skv);
        // O-projection: A = attn out (aliases qkv[0]), Bt = wo^T
        gemm_bf16<<<dim3(8, 16, 1), blk, 0, stream>>>(
            qkv, Wt + 3 * MEL, out4 + (size_t)b * SH, 2048, 0, 0);
    }
    gate_fuse<<<dim3(S), blk, 0, stream>>>(out4, gw, gb, out);
}

// Round 3
// 204.343 us; speedup vs baseline: 18.3564x; 1.9253x over previous
//
#include <hip/hip_runtime.h>

#define S 2048
#define H 1024
#define NH 16
#define HD 64
#define WIN 512
#define SCALE 0.125f

typedef unsigned short u16;
typedef __attribute__((ext_vector_type(8))) short bfrag;   // 8 bf16 (4 VGPRs)
typedef __attribute__((ext_vector_type(4))) float facc;    // 4 f32 acc
typedef __attribute__((ext_vector_type(4))) unsigned short u16x4;

// ---- workspace layout (u16 elements) --------------------------------------
// [WT 8M][XB 2M][MEMB .5M][PERB 64K][Q0..Q3 8M][K0,V0,K1,V1 8M][K2,V2 1M][K3,V3 128K]
// total 27.6875M el = 55.4 MB
constexpr size_t M1   = 1u << 20;
constexpr size_t WTO  = 0;
constexpr size_t XBO  = 8 * M1;
constexpr size_t MEMBO= 10 * M1;
constexpr size_t PERBO= MEMBO + (M1 >> 1);
constexpr size_t QO   = PERBO + (M1 >> 4);
constexpr size_t KVO  = QO + 8 * M1;          // K0,V0,K1,V1 ; later out4
constexpr size_t K2O  = KVO + 8 * M1;
constexpr size_t V2O  = K2O + (M1 >> 1);
constexpr size_t K3O  = V2O + (M1 >> 1);
constexpr size_t V3O  = K3O + (M1 >> 4);

__device__ __forceinline__ u16 f2bf(float f) {
    union { float f; unsigned u; } v; v.f = f;
    unsigned r = v.u + 0x7fffu + ((v.u >> 16) & 1u);   // RNE
    return (u16)(r >> 16);
}
__device__ __forceinline__ float bf2f(u16 b) {
    union { unsigned u; float f; } v; v.u = ((unsigned)b) << 16;
    return v.f;
}

// ---------------------------------------------------------------------------
// fp32 -> bf16 cast, 8 elems/thread
// ---------------------------------------------------------------------------
__global__ __launch_bounds__(256)
void cast_bf16(const float* __restrict__ in, u16* __restrict__ out, int n8) {
    int i = blockIdx.x * 256 + threadIdx.x;
    if (i >= n8) return;
    const float4* p = reinterpret_cast<const float4*>(in) + (size_t)i * 2;
    float4 a = p[0], b = p[1];
    u16x4 o0, o1;
    o0[0] = f2bf(a.x); o0[1] = f2bf(a.y); o0[2] = f2bf(a.z); o0[3] = f2bf(a.w);
    o1[0] = f2bf(b.x); o1[1] = f2bf(b.y); o1[2] = f2bf(b.z); o1[3] = f2bf(b.w);
    u16x4* q = reinterpret_cast<u16x4*>(out) + (size_t)i * 2;
    q[0] = o0; q[1] = o1;
}

// ---------------------------------------------------------------------------
// Wt[z][n][k] = W_z[k][n] as bf16 (transpose+cast), 64x64 LDS tiles, z = 0..3
// ---------------------------------------------------------------------------
__global__ __launch_bounds__(256)
void transp_cast(const float* __restrict__ w0, const float* __restrict__ w1,
                 const float* __restrict__ w2, const float* __restrict__ w3,
                 u16* __restrict__ wt) {
    __shared__ float t[64][65];
    const float* w = blockIdx.z == 0 ? w0 : blockIdx.z == 1 ? w1
                   : blockIdx.z == 2 ? w2 : w3;
    u16* o = wt + (size_t)blockIdx.z * (1024 * 1024);
    const int kt = blockIdx.y * 64, nt = blockIdx.x * 64;
    const int r = threadIdx.x >> 4, c4 = (threadIdx.x & 15) * 4;
#pragma unroll
    for (int p = 0; p < 4; p++) {
        float4 v = *reinterpret_cast<const float4*>(
            &w[(size_t)(kt + r + p * 16) * 1024 + nt + c4]);
        t[r + p * 16][c4 + 0] = v.x; t[r + p * 16][c4 + 1] = v.y;
        t[r + p * 16][c4 + 2] = v.z; t[r + p * 16][c4 + 3] = v.w;
    }
    __syncthreads();
#pragma unroll
    for (int p = 0; p < 4; p++) {
        int nn = r + p * 16;
        u16x4 ov;
        ov[0] = f2bf(t[c4 + 0][nn]); ov[1] = f2bf(t[c4 + 1][nn]);
        ov[2] = f2bf(t[c4 + 2][nn]); ov[3] = f2bf(t[c4 + 3][nn]);
        *reinterpret_cast<u16x4*>(&o[(size_t)(nt + nn) * 1024 + kt + c4]) = ov;
    }
}

// ---------------------------------------------------------------------------
// bf16 MFMA GEMM: C[M,1024] = scl * (A[M,1024] @ W), Bt[n][k] = W[k][n].
// 128x128 tile, BK=64, 4 waves (2x2, 64x64 each), mfma_f32_16x16x32_bf16.
// LDS XOR chunk-swizzle -> conflict-free ds_read_b128 fragments.
// z: A += z*sA, Bt += z*sB, C += z*sC; scl = SCALE if bit z of scaleMask.
// ---------------------------------------------------------------------------
__global__ __launch_bounds__(256)
void gemm_bf16(const u16* __restrict__ A, const u16* __restrict__ Bt,
               u16* __restrict__ C, int M, long sA, long sB, long sC,
               int scaleMask) {
    __shared__ __align__(16) u16 sa[128 * 64];
    __shared__ __align__(16) u16 sb[128 * 64];
    A  += (size_t)blockIdx.z * sA;
    Bt += (size_t)blockIdx.z * sB;
    C  += (size_t)blockIdx.z * sC;
    const float scl = ((scaleMask >> blockIdx.z) & 1) ? SCALE : 1.0f;
    const int tid = threadIdx.x;
    const int wid = tid >> 6, lane = tid & 63;
    const int lhi = lane >> 4, llo = lane & 15;
    const int wm = wid >> 1, wn = wid & 1;
    const int row0 = blockIdx.y * 128, col0 = blockIdx.x * 128;

    facc acc[4][4];
#pragma unroll
    for (int i = 0; i < 4; i++)
#pragma unroll
        for (int j = 0; j < 4; j++)
#pragma unroll
            for (int k = 0; k < 4; k++) acc[i][j][k] = 0.f;

    int arow[4];
#pragma unroll
    for (int j = 0; j < 4; j++) {
        int r = (j * 256 + tid) >> 3;
        int ar = row0 + r; if (ar > M - 1) ar = M - 1;   // clamp (M<128 tiles)
        arow[j] = ar;
    }
    bfrag ra[4], rb[4];
    auto load_tile = [&](int k0) {
#pragma unroll
        for (int j = 0; j < 4; j++) {
            int idx = j * 256 + tid;
            int c = idx & 7, r = idx >> 3;
            ra[j] = *reinterpret_cast<const bfrag*>(&A[(size_t)arow[j] * 1024 + k0 + c * 8]);
            rb[j] = *reinterpret_cast<const bfrag*>(&Bt[(size_t)(col0 + r) * 1024 + k0 + c * 8]);
        }
    };
    load_tile(0);
    for (int kt = 0; kt < 16; kt++) {
        __syncthreads();
#pragma unroll
        for (int j = 0; j < 4; j++) {
            int idx = j * 256 + tid;
            int c = idx & 7, r = idx >> 3;
            int p = c ^ (r & 7);
            *reinterpret_cast<bfrag*>(&sa[r * 64 + p * 8]) = ra[j];
            *reinterpret_cast<bfrag*>(&sb[r * 64 + p * 8]) = rb[j];
        }
        __syncthreads();
        if (kt < 15) load_tile((kt + 1) * 64);   // prefetch overlaps compute
#pragma unroll
        for (int ks = 0; ks < 2; ks++) {
            bfrag af[4], bfv[4];
#pragma unroll
            for (int mf = 0; mf < 4; mf++) {
                int r = wm * 64 + mf * 16 + llo;
                int p = (ks * 4 + lhi) ^ (r & 7);
                af[mf] = *reinterpret_cast<const bfrag*>(&sa[r * 64 + p * 8]);
            }
#pragma unroll
            for (int nf = 0; nf < 4; nf++) {
                int r = wn * 64 + nf * 16 + llo;
                int p = (ks * 4 + lhi) ^ (r & 7);
                bfv[nf] = *reinterpret_cast<const bfrag*>(&sb[r * 64 + p * 8]);
            }
            __builtin_amdgcn_s_setprio(1);
#pragma unroll
            for (int mf = 0; mf < 4; mf++)
#pragma unroll
                for (int nf = 0; nf < 4; nf++)
                    acc[mf][nf] = __builtin_amdgcn_mfma_f32_16x16x32_bf16(
                        af[mf], bfv[nf], acc[mf][nf], 0, 0, 0);
            __builtin_amdgcn_s_setprio(0);
        }
    }
#pragma unroll
    for (int mf = 0; mf < 4; mf++) {
#pragma unroll
        for (int r = 0; r < 4; r++) {
            int row = row0 + wm * 64 + mf * 16 + lhi * 4 + r;
            if (row < M) {
#pragma unroll
                for (int nf = 0; nf < 4; nf++) {
                    int col = col0 + wn * 64 + nf * 16 + llo;
                    C[(size_t)row * 1024 + col] = f2bf(acc[mf][nf][r] * scl);
                }
            }
        }
    }
}

// ---------------------------------------------------------------------------
// Merged flash attention, all 4 branches in ONE dispatch (2048 blocks).
// Block = 4 waves x 16 query rows (QBLK=64), KBLK=64. LPT block order:
// heavy causal q-tiles first. Q pre-scaled by 1/sqrt(d). K/V reg-prefetch.
// O written in-place over Q (block-private region).
// ---------------------------------------------------------------------------
__global__ __launch_bounds__(256)
void attn_merged(u16* __restrict__ ws) {
    __shared__ __align__(16) u16 ksm[64 * 64];
    __shared__ __align__(16) u16 vtm[64 * 64];
    __shared__ __align__(16) u16 psm[4 * 16 * 64];

    int blk = blockIdx.x;
    int branch, h, qt;
    if (blk < 512)       { branch = 1; qt = 31 - (blk >> 4); h = blk & 15; }
    else if (blk < 1024) { int t = blk - 512;  branch = 0; qt = 31 - (t >> 4); h = t & 15; }
    else if (blk < 1536) { int t = blk - 1024; branch = 2; qt = t >> 4; h = t & 15; }
    else                 { int t = blk - 1536; branch = 3; qt = t >> 4; h = t & 15; }

    size_t kb, vb; int Skv, mask;
    if (branch == 0)      { kb = KVO;          vb = KVO + 2 * M1; Skv = 2048; mask = 2; }
    else if (branch == 1) { kb = KVO + 4 * M1; vb = KVO + 6 * M1; Skv = 2048; mask = 1; }
    else if (branch == 2) { kb = K2O;          vb = V2O;          Skv = 512;  mask = 0; }
    else                  { kb = K3O;          vb = V3O;          Skv = 64;   mask = 0; }
    const u16* Kp = ws + kb;
    const u16* Vp = ws + vb;
    u16* Qp = ws + QO + (size_t)branch * 2 * M1;

    const int tid = threadIdx.x, wid = tid >> 6, lane = tid & 63;
    const int lhi = lane >> 4, llo = lane & 15;
    const int q0 = qt * 64;
    const int hoff = h * 64;

    bfrag qf[2];
    {
        const u16* qp = &Qp[(size_t)(q0 + wid * 16 + llo) * 1024 + hoff + lhi * 8];
        qf[0] = *reinterpret_cast<const bfrag*>(qp);
        qf[1] = *reinterpret_cast<const bfrag*>(qp + 32);
    }
    facc acc_o[4];
    float m_r[4], l_r[4];
#pragma unroll
    for (int r = 0; r < 4; r++) { m_r[r] = -1e30f; l_r[r] = 0.f; }
#pragma unroll
    for (int nf = 0; nf < 4; nf++)
#pragma unroll
        for (int k = 0; k < 4; k++) acc_o[nf][k] = 0.f;

    const int ktEnd = (mask >= 1) ? (qt + 1) : (Skv >> 6);
    const int ktBeg = (mask == 2 && q0 >= WIN) ? ((q0 - WIN) >> 6) : 0;
    const int vkey = tid & 63, vdb = (tid >> 6) * 16;

    bfrag rk[2], rv[2];
    auto load_kv = [&](int kt) {
#pragma unroll
        for (int j = 0; j < 2; j++) {
            int idx = j * 256 + tid;
            int key = idx >> 3, c = idx & 7;
            rk[j] = *reinterpret_cast<const bfrag*>(
                &Kp[(size_t)(kt * 64 + key) * 1024 + hoff + c * 8]);
        }
        const u16* vp = &Vp[(size_t)(kt * 64 + vkey) * 1024 + hoff + vdb];
        rv[0] = *reinterpret_cast<const bfrag*>(vp);
        rv[1] = *reinterpret_cast<const bfrag*>(vp + 8);
    };
    load_kv(ktBeg);

    for (int kt = ktBeg; kt < ktEnd; kt++) {
        __syncthreads();   // all waves done reading prev tile's ksm/vtm
#pragma unroll
        for (int j = 0; j < 2; j++) {
            int idx = j * 256 + tid;
            int key = idx >> 3, c = idx & 7;
            *reinterpret_cast<bfrag*>(&ksm[key * 64 + (c ^ (key & 7)) * 8]) = rk[j];
        }
        {
            int kc = vkey >> 3, kp = vkey & 7;
#pragma unroll
            for (int j = 0; j < 2; j++)
#pragma unroll
                for (int i = 0; i < 8; i++) {
                    int d = vdb + j * 8 + i;
                    vtm[d * 64 + ((kc ^ (d & 7)) * 8 + kp)] = (u16)(unsigned short)rv[j][i];
                }
        }
        __syncthreads();
        if (kt + 1 < ktEnd) load_kv(kt + 1);   // prefetch overlaps compute

        // S = Q K^T
        facc sc[4];
#pragma unroll
        for (int nf = 0; nf < 4; nf++)
#pragma unroll
            for (int k = 0; k < 4; k++) sc[nf][k] = 0.f;
        __builtin_amdgcn_s_setprio(1);
#pragma unroll
        for (int nf = 0; nf < 4; nf++) {
#pragma unroll
            for (int ks = 0; ks < 2; ks++) {
                int r = nf * 16 + llo;
                int p = (ks * 4 + lhi) ^ (r & 7);
                bfrag kf = *reinterpret_cast<const bfrag*>(&ksm[r * 64 + p * 8]);
                sc[nf] = __builtin_amdgcn_mfma_f32_16x16x32_bf16(qf[ks], kf, sc[nf], 0, 0, 0);
            }
        }
        __builtin_amdgcn_s_setprio(0);
        float s[4][4];
#pragma unroll
        for (int nf = 0; nf < 4; nf++)
#pragma unroll
            for (int r = 0; r < 4; r++) s[nf][r] = sc[nf][r];

        const bool diag = (mask >= 1) && (kt == qt);
        const bool wedge = (mask == 2) && (q0 >= WIN) && (kt == ktBeg);
        if (diag || wedge) {
#pragma unroll
            for (int nf = 0; nf < 4; nf++)
#pragma unroll
                for (int r = 0; r < 4; r++) {
                    int key = kt * 64 + nf * 16 + llo;
                    int qi = q0 + wid * 16 + lhi * 4 + r;
                    if ((diag && key > qi) || (wedge && (qi - key) > WIN))
                        s[nf][r] = -1e30f;
                }
        }
        // online softmax, rows reduce across 16-lane groups
        float alpha[4];
#pragma unroll
        for (int r = 0; r < 4; r++) {
            float mx = fmaxf(fmaxf(s[0][r], s[1][r]), fmaxf(s[2][r], s[3][r]));
            mx = fmaxf(mx, __shfl_xor(mx, 1));
            mx = fmaxf(mx, __shfl_xor(mx, 2));
            mx = fmaxf(mx, __shfl_xor(mx, 4));
            mx = fmaxf(mx, __shfl_xor(mx, 8));
            float mn = fmaxf(m_r[r], mx);
            alpha[r] = __expf(m_r[r] - mn);
            m_r[r] = mn;
            float rs = 0.f;
#pragma unroll
            for (int nf = 0; nf < 4; nf++) {
                float pv = __expf(s[nf][r] - mn);
                s[nf][r] = pv; rs += pv;
            }
            rs += __shfl_xor(rs, 1);
            rs += __shfl_xor(rs, 2);
            rs += __shfl_xor(rs, 4);
            rs += __shfl_xor(rs, 8);
            l_r[r] = l_r[r] * alpha[r] + rs;
        }
#pragma unroll
        for (int nf = 0; nf < 4; nf++)
#pragma unroll
            for (int r = 0; r < 4; r++) acc_o[nf][r] *= alpha[r];

        // P (D layout) -> per-wave LDS (swizzled) -> A-fragment layout
        u16* pw = &psm[wid * 1024];
#pragma unroll
        for (int nf = 0; nf < 4; nf++) {
            int kc = nf * 2 + (llo >> 3), kp = llo & 7;
#pragma unroll
            for (int r = 0; r < 4; r++) {
                int row = lhi * 4 + r;
                pw[row * 64 + ((kc ^ (row & 7)) * 8 + kp)] = f2bf(s[nf][r]);
            }
        }
        // PV (wave-local P, no barrier needed)
        __builtin_amdgcn_s_setprio(1);
#pragma unroll
        for (int ks = 0; ks < 2; ks++) {
            int pp = (ks * 4 + lhi) ^ (llo & 7);
            bfrag pf = *reinterpret_cast<const bfrag*>(&pw[llo * 64 + pp * 8]);
#pragma unroll
            for (int nf = 0; nf < 4; nf++) {
                int d = nf * 16 + llo;
                int vp2 = (ks * 4 + lhi) ^ (d & 7);
                bfrag vf = *reinterpret_cast<const bfrag*>(&vtm[d * 64 + vp2 * 8]);
                acc_o[nf] = __builtin_amdgcn_mfma_f32_16x16x32_bf16(pf, vf, acc_o[nf], 0, 0, 0);
            }
        }
        __builtin_amdgcn_s_setprio(0);
    }
#pragma unroll
    for (int r = 0; r < 4; r++) {
        float inv = 1.f / l_r[r];
#pragma unroll
        for (int nf = 0; nf < 4; nf++) {
            int row = q0 + wid * 16 + lhi * 4 + r;
            int col = hoff + nf * 16 + llo;
            Qp[(size_t)row * 1024 + col] = f2bf(acc_o[nf][r] * inv);
        }
    }
}

// ---------------------------------------------------------------------------
// Gate + fuse (out4 in bf16): g = softmax(concat(outs) @ gate_w + gate_b),
// out = sum_b g[b] * outs[b]. One block per token.
// ---------------------------------------------------------------------------
__global__ __launch_bounds__(256)
void gate_fuse(const u16* __restrict__ o4, const float* __restrict__ gw,
               const float* __restrict__ gb, float* __restrict__ out) {
    const size_t SHsz = (size_t)S * H;
    const int s = blockIdx.x, tid = threadIdx.x;
    const u16* ob0 = o4 + (size_t)s * H;
    float p[4] = {0.f, 0.f, 0.f, 0.f};
    for (int b = 0; b < 4; b++) {
        const u16* obb = ob0 + b * 2 * M1;
        const float* gwb = gw + (size_t)b * H * 4;
        for (int i = tid; i < H; i += 256) {
            float xv = bf2f(obb[i]);
            float4 g4 = *reinterpret_cast<const float4*>(&gwb[(size_t)i * 4]);
            p[0] += xv * g4.x; p[1] += xv * g4.y;
            p[2] += xv * g4.z; p[3] += xv * g4.w;
        }
    }
#pragma unroll
    for (int off = 1; off < 64; off <<= 1)
#pragma unroll
        for (int j = 0; j < 4; j++) p[j] += __shfl_xor(p[j], off);
    __shared__ float red[4][4];
    if ((tid & 63) == 0) {
        int w = tid >> 6;
#pragma unroll
        for (int j = 0; j < 4; j++) red[w][j] = p[j];
    }
    __syncthreads();
    float gl[4];
#pragma unroll
    for (int j = 0; j < 4; j++)
        gl[j] = gb[j] + red[0][j] + red[1][j] + red[2][j] + red[3][j];
    float mx = fmaxf(fmaxf(gl[0], gl[1]), fmaxf(gl[2], gl[3]));
    float e[4]; float tot = 0.f;
#pragma unroll
    for (int j = 0; j < 4; j++) { e[j] = __expf(gl[j] - mx); tot += e[j]; }
    float inv = 1.f / tot;
    int d = tid * 4;
    float4 rv; rv.x = rv.y = rv.z = rv.w = 0.f;
#pragma unroll
    for (int b = 0; b < 4; b++) {
        const u16* obb = ob0 + b * 2 * M1 + d;
        float wgt = e[b] * inv;
        rv.x += wgt * bf2f(obb[0]);
        rv.y += wgt * bf2f(obb[1]);
        rv.z += wgt * bf2f(obb[2]);
        rv.w += wgt * bf2f(obb[3]);
    }
    *reinterpret_cast<float4*>(&out[(size_t)s * H + d]) = rv;
}

// ---------------------------------------------------------------------------
// Orchestration:
//  A: Wt8 <- {wq0..3, wk0,wv0,wk1,wv1}; big z=8 GEMM -> Q0..3 (x SCALE), K0,V0,K1,V1
//  B: Wt4 <- {wk2,wv2,wk3,wv3}; mem z=2 GEMM; per z=2 GEMM
//  C: merged attn (1 dispatch, in-place O over Q)
//  D: Wt4 <- {wo0..3}; O-proj z=4 GEMM -> out4 (over K/V region)
//  E: gate_fuse
// ---------------------------------------------------------------------------
extern "C" void kernel_launch(void* const* d_in, const int* in_sizes, int n_in,
                              void* d_out, int out_size, void* d_ws, size_t ws_size,
                              hipStream_t stream) {
    const float* Wm[16];
    for (int i = 0; i < 16; i++) Wm[i] = (const float*)d_in[i];
    const float* gw = (const float*)d_in[16];
    const float* gb = (const float*)d_in[17];
    const float* x = (const float*)d_in[18];
    const float* mem = (const float*)d_in[19];
    const float* per = (const float*)d_in[20];
    float* out = (float*)d_out;
    u16* ws = (u16*)d_ws;
    const size_t SH = (size_t)S * H;

    dim3 blk(256);
    cast_bf16<<<dim3(1024), blk, 0, stream>>>(x, ws + XBO, (int)(SH / 8));
    cast_bf16<<<dim3(256), blk, 0, stream>>>(mem, ws + MEMBO, 512 * 1024 / 8);
    cast_bf16<<<dim3(32), blk, 0, stream>>>(per, ws + PERBO, 64 * 1024 / 8);

    // Phase A
    transp_cast<<<dim3(16, 16, 4), blk, 0, stream>>>(
        Wm[0], Wm[4], Wm[8], Wm[12], ws + WTO);            // wq local/long/mem/per
    transp_cast<<<dim3(16, 16, 4), blk, 0, stream>>>(
        Wm[1], Wm[2], Wm[5], Wm[6], ws + WTO + 4 * M1);    // wk0,wv0,wk1,wv1
    gemm_bf16<<<dim3(8, 16, 8), blk, 0, stream>>>(
        ws + XBO, ws + WTO, ws + QO, 2048, 0, (long)M1, (long)(2 * M1), 0xF);

    // Phase B
    transp_cast<<<dim3(16, 16, 4), blk, 0, stream>>>(
        Wm[9], Wm[10], Wm[13], Wm[14], ws + WTO);          // wk2,wv2,wk3,wv3
    gemm_bf16<<<dim3(8, 4, 2), blk, 0, stream>>>(
        ws + MEMBO, ws + WTO, ws + K2O, 512, 0, (long)M1, (long)(M1 >> 1), 0);
    gemm_bf16<<<dim3(8, 1, 2), blk, 0, stream>>>(
        ws + PERBO, ws + WTO + 2 * M1, ws + K3O, 64, 0, (long)M1, (long)(M1 >> 4), 0);

    // Phase C
    attn_merged<<<dim3(2048), blk, 0, stream>>>(ws);

    // Phase D
    transp_cast<<<dim3(16, 16, 4), blk, 0, stream>>>(
        Wm[3], Wm[7], Wm[11], Wm[15], ws + WTO);           // wo local/long/mem/per
    gemm_bf16<<<dim3(8, 16, 4), blk, 0, stream>>>(
        ws + QO, ws + WTO, ws + KVO, 2048, (long)(2 * M1), (long)M1, (long)(2 * M1), 0);

    // Phase E
    gate_fuse<<<dim3(S), blk, 0, stream>>>(ws + KVO, gw, gb, out);
}